// Round 4
// baseline (376.702 us; speedup 1.0000x reference)
//
#include <hip/hip_runtime.h>

// (B, C, H, W) = (8, 256, 64, 64); N = 4096; QK dim = 32.
#define NPIX 4096
#define CCH  256
#define CN   (CCH * NPIX)

typedef __attribute__((ext_vector_type(8)))  short short8;   // 8 bf16 (4 VGPRs)
typedef __attribute__((ext_vector_type(4)))  float f32x4;    // 16x16 C/D frag
typedef __attribute__((ext_vector_type(16))) float f32x16;   // 32x32 C/D frag

union U48 { uint4 u; short8 s; };

// pack two fp32 -> bf16 pair, truncation: single v_perm_b32
__device__ __forceinline__ unsigned pk2t(float lo, float hi) {
    return __builtin_amdgcn_perm(__float_as_uint(hi), __float_as_uint(lo),
                                 0x07060302u);
}
__device__ __forceinline__ unsigned short bf16t(float f) {
    return (unsigned short)(__float_as_uint(f) >> 16);
}

// Raw workgroup barrier: drains LDS ops only (global loads stay in flight).
__device__ __forceinline__ void lgkm_barrier() {
    asm volatile("s_waitcnt lgkmcnt(0)" ::: "memory");
    __builtin_amdgcn_s_barrier();
    asm volatile("" ::: "memory");
}

// 1/sqrt(32) * log2(e): scores come out in log2 domain -> v_exp_f32 direct
#define QSCALE 0.25503494f

// ---------------------------------------------------------------------------
// Fused projections (unchanged from verified r3 version).
// ---------------------------------------------------------------------------
__global__ __launch_bounds__(256, 2) void proj_fused(
    const float* __restrict__ xg, const float* __restrict__ Wq,
    const float* __restrict__ Wk, const float* __restrict__ Wv,
    unsigned short* __restrict__ qo, unsigned short* __restrict__ ko,
    unsigned short* __restrict__ vo)
{
    __shared__ uint4 ws4[64 * 32];   // W chunk: 64 d-rows x 32 bf16-granules
    const int tid = threadIdx.x;
    const int n0 = blockIdx.y * 64;
    const int b  = blockIdx.x;
    const int lane = tid & 63, w = tid >> 6;
    const int q = lane >> 4, nlo = lane & 15;
    const float* xb = xg + (size_t)b * CN;

    U48 A[8];
#pragma unroll
    for (int ks = 0; ks < 8; ++ks) {
        const float* xc = xb + (size_t)(ks * 32 + q * 8) * NPIX
                             + (n0 + w * 16 + nlo);
        float v0 = xc[0],        v1 = xc[NPIX],     v2 = xc[2 * NPIX],
              v3 = xc[3 * NPIX], v4 = xc[4 * NPIX], v5 = xc[5 * NPIX],
              v6 = xc[6 * NPIX], v7 = xc[7 * NPIX];
        A[ks].u = make_uint4(pk2t(v0, v1), pk2t(v2, v3),
                             pk2t(v4, v5), pk2t(v6, v7));
    }

    const int dd = tid >> 2, s4 = tid & 3;
    for (int cc = 0; cc < 5; ++cc) {
        lgkm_barrier();
        {
            const float* wr;
            if (cc == 0) wr = (dd < 32) ? (Wq + dd * CCH) : (Wk + (dd - 32) * CCH);
            else         wr = Wv + (size_t)((cc - 1) * 64 + dd) * CCH;
#pragma unroll
            for (int gi = 0; gi < 8; ++gi) {
                const int c = s4 * 64 + gi * 8;
                float4 a  = *(const float4*)(wr + c);
                float4 bb = *(const float4*)(wr + c + 4);
                ws4[dd * 32 + s4 * 8 + (gi ^ (dd & 7))] =
                    make_uint4(pk2t(a.x, a.y), pk2t(a.z, a.w),
                               pk2t(bb.x, bb.y), pk2t(bb.z, bb.w));
            }
        }
        lgkm_barrier();

        f32x4 acc[4];
#pragma unroll
        for (int dt = 0; dt < 4; ++dt) acc[dt] = (f32x4){0.f, 0.f, 0.f, 0.f};
#pragma unroll
        for (int ks = 0; ks < 8; ++ks)
#pragma unroll
            for (int dt = 0; dt < 4; ++dt) {
                U48 Bf;
                Bf.u = ws4[(dt * 16 + nlo) * 32 + (ks >> 1) * 8
                           + (((ks & 1) * 4 + q) ^ (nlo & 7))];
                acc[dt] = __builtin_amdgcn_mfma_f32_16x16x32_bf16(
                    A[ks].s, Bf.s, acc[dt], 0, 0, 0);
            }

        if (cc == 0) {
#pragma unroll
            for (int dt = 0; dt < 4; ++dt) {
                const int d = dt * 16 + nlo;
#pragma unroll
                for (int r = 0; r < 4; ++r) {
                    const int n = n0 + w * 16 + q * 4 + r;
                    if (d < 32)
                        qo[((size_t)b * NPIX + n) * 32 + d] =
                            bf16t(acc[dt][r] * QSCALE);
                    else
                        ko[((size_t)b * NPIX + n) * 32 + (d - 32)] =
                            bf16t(acc[dt][r]);
                }
            }
        } else {
#pragma unroll
            for (int dt = 0; dt < 4; ++dt) {
                const int c = (cc - 1) * 64 + dt * 16 + nlo;
                const int n = n0 + w * 16 + q * 4;
                *(uint2*)(vo + ((size_t)b * CCH + c) * (size_t)NPIX + n) =
                    make_uint2(pk2t(acc[dt][0], acc[dt][1]),
                               pk2t(acc[dt][2], acc[dt][3]));
            }
        }
    }
}

// ---------------------------------------------------------------------------
// Flash attention v6: WAVE-AUTONOMOUS.  Zero LDS, zero barriers in the loop.
// 32x32x16 MFMAs; swapped QK^T (A=K, B=Q) puts 16 key-scores for ONE query
// column in each lane (C: col=lane&31, row=(reg&3)+8*(reg>>2)+4*(lane>>5)).
// P->bf16 via pk2t pairs; h-half redistribution for the PV B-operand via
// v_permlane32_swap_b32: for k-step s, parity p: swap(pk[4s+p], pk[4s+2+p])
// yields B-frag regs j=p (vdst') and j=2+p (vsrc') exactly:
//   B reg j covers keys s*16+8h+2j; source C-reg i=4s+2h+p lives at half
//   h_src=j>>1, and the swap moves vdst_hi<->vsrc_lo.
// Wave (wq,wc) owns queries [n0+wq*32,+32) x channels [wc*128,+128):
// acc = 4 x f32x16.  l-reduce = one shfl_xor(32).  Waves free-run: no
// convoy, latency hidden by wave diversity instead of intra-block phasing.
// ---------------------------------------------------------------------------
__global__ __launch_bounds__(256, 2) void flash_v6(
    const unsigned short* __restrict__ qg, const unsigned short* __restrict__ kg,
    const unsigned short* __restrict__ vg, const float* __restrict__ xg,
    const float* __restrict__ gp, float* __restrict__ outg)
{
    const int tid = threadIdx.x, lane = tid & 63, w = tid >> 6;
    const int l31 = lane & 31, h = lane >> 5;
    const int wq = w & 1, wc = w >> 1;
    const int n0 = blockIdx.y * 64, b = blockIdx.x;
    const int nq = n0 + wq * 32 + l31;   // this lane's query column

    const unsigned short* qb = qg + (size_t)b * NPIX * 32;
    const unsigned short* kb = kg + (size_t)b * NPIX * 32;
    const unsigned short* vb = vg + (size_t)b * CN;

    // Q B-frags (B: col=lane&31=query, k=dim=(lane>>5)*8+j), two k-steps
    U48 Bq[2];
    Bq[0].u = *(const uint4*)(qb + (size_t)nq * 32 + h * 8);
    Bq[1].u = *(const uint4*)(qb + (size_t)nq * 32 + 16 + h * 8);

    const f32x16 z16 = {0.f, 0.f, 0.f, 0.f, 0.f, 0.f, 0.f, 0.f,
                        0.f, 0.f, 0.f, 0.f, 0.f, 0.f, 0.f, 0.f};
    f32x16 acc[4];
#pragma unroll
    for (int ct = 0; ct < 4; ++ct) acc[ct] = z16;
    float lacc = 0.f;

    // V row pointers: A-frag row = channel = wc*128+ct*32+l31, k-granule h*8
    const unsigned short* vrow[4];
#pragma unroll
    for (int ct = 0; ct < 4; ++ct)
        vrow[ct] = vb + (size_t)(wc * 128 + ct * 32 + l31) * NPIX + h * 8;

    // K A-frags (A: row=lane&31=key, k=dim), double-buffered across bodies
    U48 Ak[2][2];
    Ak[0][0].u = *(const uint4*)(kb + (size_t)l31 * 32 + h * 8);
    Ak[0][1].u = *(const uint4*)(kb + (size_t)l31 * 32 + 16 + h * 8);

    auto body = [&](int m0, int bi) {
        // V frags for this 32-key body (issue early; consumed after softmax)
        U48 Av[2][4];
#pragma unroll
        for (int s = 0; s < 2; ++s)
#pragma unroll
            for (int ct = 0; ct < 4; ++ct)
                Av[s][ct].u = *(const uint4*)(vrow[ct] + m0 + s * 16);

        // S^T = K . Q^T  (accumulate over dim via 2 k-steps)
        f32x16 St = __builtin_amdgcn_mfma_f32_32x32x16_bf16(
            Ak[bi][0].s, Bq[0].s, z16, 0, 0, 0);
        St = __builtin_amdgcn_mfma_f32_32x32x16_bf16(
            Ak[bi][1].s, Bq[1].s, St, 0, 0, 0);

        // prefetch next body's K frags
        const int mn = m0 + 32;
        if (mn < NPIX) {
            Ak[bi ^ 1][0].u = *(const uint4*)(kb + (size_t)(mn + l31) * 32 + h * 8);
            Ak[bi ^ 1][1].u =
                *(const uint4*)(kb + (size_t)(mn + l31) * 32 + 16 + h * 8);
        }

        // softmax (log2 domain, no max-tracking): p = exp2(S), l += sum
        float p[16];
#pragma unroll
        for (int r = 0; r < 16; ++r) p[r] = __builtin_amdgcn_exp2f(St[r]);
        float s0 = (p[0] + p[1]) + (p[2] + p[3]);
        float s1 = (p[4] + p[5]) + (p[6] + p[7]);
        float s2 = (p[8] + p[9]) + (p[10] + p[11]);
        float s3 = (p[12] + p[13]) + (p[14] + p[15]);
        lacc += (s0 + s1) + (s2 + s3);

        unsigned pk[8];
#pragma unroll
        for (int i = 0; i < 8; ++i) pk[i] = pk2t(p[2 * i], p[2 * i + 1]);

        // PV: per k-step s, build B-frag via 2 permlane32_swap, then 4 MFMAs
#pragma unroll
        for (int s = 0; s < 2; ++s) {
            unsigned a0 = pk[4 * s + 0], b0 = pk[4 * s + 2];
            unsigned a1 = pk[4 * s + 1], b1 = pk[4 * s + 3];
            asm volatile("v_permlane32_swap_b32 %0, %1" : "+v"(a0), "+v"(b0));
            asm volatile("v_permlane32_swap_b32 %0, %1" : "+v"(a1), "+v"(b1));
            U48 Bp;
            Bp.u = make_uint4(a0, a1, b0, b1);   // regs j=0,1,2,3
#pragma unroll
            for (int ct = 0; ct < 4; ++ct)
                acc[ct] = __builtin_amdgcn_mfma_f32_32x32x16_bf16(
                    Av[s][ct].s, Bp.s, acc[ct], 0, 0, 0);
        }
    };

    for (int m0 = 0; m0 < NPIX; m0 += 64) {   // static buffer indices
        body(m0, 0);
        body(m0 + 32, 1);
    }

    // ---- l: own half-keys + h-partner half  (same query column)
    const float l = lacc + __shfl_xor(lacc, 32);
    const float linv = 1.0f / l;

    // ---- epilogue: out = gamma * (O / l) + x
    const float gamma = gp[0];
    const float* xb2 = xg + (size_t)b * CN;
    float* ob = outg + (size_t)b * CN;
#pragma unroll
    for (int ct = 0; ct < 4; ++ct)
#pragma unroll
        for (int r = 0; r < 16; ++r) {
            const int c = wc * 128 + ct * 32 + (r & 3) + 8 * (r >> 2) + 4 * h;
            const size_t off = (size_t)c * NPIX + nq;
            ob[off] = fmaf(gamma, acc[ct][r] * linv, xb2[off]);
        }
}

// ---------------------------------------------------------------------------
extern "C" void kernel_launch(void* const* d_in, const int* in_sizes, int n_in,
                              void* d_out, int out_size, void* d_ws, size_t ws_size,
                              hipStream_t stream) {
    const float* x     = (const float*)d_in[0];   // (8,256,64,64)
    const float* Wq    = (const float*)d_in[1];   // (32,256)
    const float* Wk    = (const float*)d_in[2];   // (32,256)
    const float* Wv    = (const float*)d_in[3];   // (256,256)
    const float* gamma = (const float*)d_in[4];   // (1,)

    // ws: Q (B,N,32) bf16 2MB | K (B,N,32) bf16 2MB | V (B,256,N) bf16 16MB
    unsigned short* qws = (unsigned short*)d_ws;
    unsigned short* kws = qws + (size_t)8 * NPIX * 32;
    unsigned short* vws = kws + (size_t)8 * NPIX * 32;

    // batch = blockIdx.x (fast index): all blocks of a batch on one XCD.
    proj_fused<<<dim3(8, 64), 256, 0, stream>>>(x, Wq, Wk, Wv, qws, kws, vws);
    flash_v6<<<dim3(8, 64), 256, 0, stream>>>(qws, kws, vws, x, gamma,
                                              (float*)d_out);
}

// Round 5
// 187.127 us; speedup vs baseline: 2.0131x; 2.0131x over previous
//
#include <hip/hip_runtime.h>

// (B, C, H, W) = (8, 256, 64, 64); N = 4096; QK dim = 32.
#define NPIX 4096
#define CCH  256
#define CN   (CCH * NPIX)

typedef __attribute__((ext_vector_type(8))) short  short8;  // 8 bf16 (4 VGPRs)
typedef __attribute__((ext_vector_type(4))) float  f32x4;   // MFMA C/D frag

union U48 { uint4 u; short8 s; };

// pack two fp32 -> bf16 pair, truncation: single v_perm_b32
__device__ __forceinline__ unsigned pk2t(float lo, float hi) {
    return __builtin_amdgcn_perm(__float_as_uint(hi), __float_as_uint(lo),
                                 0x07060302u);
}
__device__ __forceinline__ unsigned short bf16t(float f) {
    return (unsigned short)(__float_as_uint(f) >> 16);
}

// Raw workgroup barrier: drains LDS ops only (global loads stay in flight).
__device__ __forceinline__ void lgkm_barrier() {
    asm volatile("s_waitcnt lgkmcnt(0)" ::: "memory");
    __builtin_amdgcn_s_barrier();
    asm volatile("" ::: "memory");
}

// 1/sqrt(32) * log2(e): scores come out in log2 domain -> v_exp_f32 direct
#define QSCALE 0.25503494f

// ---------------------------------------------------------------------------
// V' layout (bf16, 16B granules): granule g = ((((b*16+cb)*128+mb)*4+q)*16+cl)
// holds keys m = mb*32+q*8 .. +8 of channel ch = cb*16+cl.  This makes the
// flash V A-frag load address = base + lane*16: 64 lanes = 1KB contiguous,
// 8 fully-used 128B lines per instruction (was: 16 quarter-used lines).
// Identified bottleneck (r2/r3/r4 invariant): per-CU distinct-cache-line
// processing on scattered loads, ~4-5 cyc/line, occupancy-independent.
// ---------------------------------------------------------------------------

// ---------------------------------------------------------------------------
// Fused projections: out^T[n][d] = sum_c x[c][n] * W[d][c] for the stacked
// D = [Wq(32) | Wk(32) | Wv(256)] in 5 chunks of 64 rows.  x A-frags are
// loaded + bf16-packed ONCE per thread and reused across all 5 chunk GEMMs.
// Block: 64 n x (64 d per chunk), 4 waves.  V stored in V' layout: each
// (cc,dt) store = fully-covered 512B contiguous span per wave.
// ---------------------------------------------------------------------------
__global__ __launch_bounds__(256, 2) void proj_fused(
    const float* __restrict__ xg, const float* __restrict__ Wq,
    const float* __restrict__ Wk, const float* __restrict__ Wv,
    unsigned short* __restrict__ qo, unsigned short* __restrict__ ko,
    unsigned short* __restrict__ vo)
{
    __shared__ uint4 ws4[64 * 32];   // W chunk: 64 d-rows x 32 bf16-granules
    const int tid = threadIdx.x;
    const int n0 = blockIdx.y * 64;
    const int b  = blockIdx.x;
    const int lane = tid & 63, w = tid >> 6;
    const int q = lane >> 4, nlo = lane & 15;
    const float* xb = xg + (size_t)b * CN;

    // ---- A-frags: x^T row n = n0+w*16+nlo, k-chunk c = ks*32+q*8..+8
    U48 A[8];
#pragma unroll
    for (int ks = 0; ks < 8; ++ks) {
        const float* xc = xb + (size_t)(ks * 32 + q * 8) * NPIX
                             + (n0 + w * 16 + nlo);
        float v0 = xc[0],        v1 = xc[NPIX],     v2 = xc[2 * NPIX],
              v3 = xc[3 * NPIX], v4 = xc[4 * NPIX], v5 = xc[5 * NPIX],
              v6 = xc[6 * NPIX], v7 = xc[7 * NPIX];
        A[ks].u = make_uint4(pk2t(v0, v1), pk2t(v2, v3),
                             pk2t(v4, v5), pk2t(v6, v7));
    }

    const int dd = tid >> 2, s4 = tid & 3;   // W staging role
    for (int cc = 0; cc < 5; ++cc) {
        lgkm_barrier();   // prior chunk's ds_reads done (consumed by MFMAs)
        {   // stage W chunk (bf16, XOR-swizzled 16B granules)
            const float* wr;
            if (cc == 0) wr = (dd < 32) ? (Wq + dd * CCH) : (Wk + (dd - 32) * CCH);
            else         wr = Wv + (size_t)((cc - 1) * 64 + dd) * CCH;
#pragma unroll
            for (int gi = 0; gi < 8; ++gi) {
                const int c = s4 * 64 + gi * 8;
                float4 a  = *(const float4*)(wr + c);
                float4 bb = *(const float4*)(wr + c + 4);
                ws4[dd * 32 + s4 * 8 + (gi ^ (dd & 7))] =
                    make_uint4(pk2t(a.x, a.y), pk2t(a.z, a.w),
                               pk2t(bb.x, bb.y), pk2t(bb.z, bb.w));
            }
        }
        lgkm_barrier();   // ws4 writes visible

        f32x4 acc[4];
#pragma unroll
        for (int dt = 0; dt < 4; ++dt) acc[dt] = (f32x4){0.f, 0.f, 0.f, 0.f};
#pragma unroll
        for (int ks = 0; ks < 8; ++ks)
#pragma unroll
            for (int dt = 0; dt < 4; ++dt) {
                U48 Bf;
                Bf.u = ws4[(dt * 16 + nlo) * 32 + (ks >> 1) * 8
                           + (((ks & 1) * 4 + q) ^ (nlo & 7))];
                acc[dt] = __builtin_amdgcn_mfma_f32_16x16x32_bf16(
                    A[ks].s, Bf.s, acc[dt], 0, 0, 0);
            }

        // ---- epilogue (C rows = n-offset q*4+r, cols = d = dt*16+nlo)
        if (cc == 0) {
#pragma unroll
            for (int dt = 0; dt < 4; ++dt) {
                const int d = dt * 16 + nlo;
#pragma unroll
                for (int r = 0; r < 4; ++r) {
                    const int n = n0 + w * 16 + q * 4 + r;
                    if (d < 32)
                        qo[((size_t)b * NPIX + n) * 32 + d] =
                            bf16t(acc[dt][r] * QSCALE);
                    else
                        ko[((size_t)b * NPIX + n) * 32 + (d - 32)] =
                            bf16t(acc[dt][r]);
                }
            }
        } else {
            // V' store: keys m = n0+w*16+q*4..+3 (uint2 = granule half q&1),
            // channel ch = (cc-1)*64 + dt*16 + nlo -> cb = (cc-1)*4+dt, cl=nlo
#pragma unroll
            for (int dt = 0; dt < 4; ++dt) {
                const int cb = (cc - 1) * 4 + dt;
                const int mb = (n0 >> 5) + (w >> 1);
                const int qc = (w & 1) * 2 + (q >> 1);
                const size_t gran =
                    ((((size_t)b * 16 + cb) * 128 + mb) * 4 + qc) * 16 + nlo;
                *(uint2*)((char*)vo + gran * 16 + (q & 1) * 8) =
                    make_uint2(pk2t(acc[dt][0], acc[dt][1]),
                               pk2t(acc[dt][2], acc[dt][3]));
            }
        }
    }
}

// ---------------------------------------------------------------------------
// Flash attention v7 = verified v5 structure (4 waves, P-LDS double-buffered,
// one lgkm-only barrier per body, K/V register double-buffered) with V reads
// from the V' fragment-contiguous layout: every V A-frag load is
// base + lane*16 (1KB contiguous per wave instruction).
// ---------------------------------------------------------------------------
__global__ __launch_bounds__(256, 2) void flash_v7(
    const unsigned short* __restrict__ qg, const unsigned short* __restrict__ kg,
    const unsigned short* __restrict__ vg, const float* __restrict__ xg,
    const float* __restrict__ gp, float* __restrict__ outg)
{
    __shared__ uint4 ps4[2][64 * 8];   // P^T: [buf][n][swizzled m-granule]
    __shared__ float ls[4][64];        // per-wave l partials

    const int tid = threadIdx.x, lane = tid & 63, w = tid >> 6;
    const int q = lane >> 4, nlo = lane & 15;
    const int n0 = blockIdx.y * 64, b = blockIdx.x;

    const unsigned short* qb = qg + (size_t)b * NPIX * 32;
    const unsigned short* kb = kg + (size_t)b * NPIX * 32;

    U48 Bq[4];   // Q^T B-frags, loop-invariant
#pragma unroll
    for (int nt = 0; nt < 4; ++nt)
        Bq[nt].u = *(const uint4*)(qb + (size_t)(n0 + nt * 16 + nlo) * 32 + q * 8);

    f32x4 acc[4][4];   // [ct][nt]; wave w owns channels w*64..+64
#pragma unroll
    for (int ct = 0; ct < 4; ++ct)
#pragma unroll
        for (int nt = 0; nt < 4; ++nt) acc[ct][nt] = (f32x4){0.f, 0.f, 0.f, 0.f};
    float lacc[4] = {0.f, 0.f, 0.f, 0.f};

    U48 AkB[2], AvB[2][2][4];   // double-buffered K/V frags
    auto load_tiles = [&](int m0, int bi) {
        AkB[bi].u = *(const uint4*)(kb + (size_t)(m0 + w * 16 + nlo) * 32 + q * 8);
        const int mb = m0 >> 5;
#pragma unroll
        for (int s = 0; s < 2; ++s)
#pragma unroll
            for (int ct = 0; ct < 4; ++ct) {
                // V' granule: cb = w*4+ct, mb+s, q, cl=nlo -> lane*16 contiguous
                const size_t gran =
                    ((((size_t)b * 16 + w * 4 + ct) * 128 + (mb + s)) * 4 + q)
                        * 16 + nlo;
                AvB[bi][s][ct].u = *(const uint4*)((const char*)vg + gran * 16);
            }
    };
    auto body = [&](int m0, int bi) {
        // S^T: 4 MFMAs, rows m = m0+w*16+q*4+r, cols n = nt*16+nlo
        f32x4 St[4];
        const f32x4 z = {0.f, 0.f, 0.f, 0.f};
#pragma unroll
        for (int nt = 0; nt < 4; ++nt)
            St[nt] = __builtin_amdgcn_mfma_f32_16x16x32_bf16(
                AkB[bi].s, Bq[nt].s, z, 0, 0, 0);

#pragma unroll
        for (int nt = 0; nt < 4; ++nt) {
            float p0 = __builtin_amdgcn_exp2f(St[nt][0]);
            float p1 = __builtin_amdgcn_exp2f(St[nt][1]);
            float p2 = __builtin_amdgcn_exp2f(St[nt][2]);
            float p3 = __builtin_amdgcn_exp2f(St[nt][3]);
            lacc[nt] += (p0 + p1) + (p2 + p3);
            const int n = nt * 16 + nlo;
            ((uint2*)ps4[bi])[n * 16 + ((w * 2 + (q >> 1)) ^ (n & 7)) * 2 + (q & 1)] =
                make_uint2(pk2t(p0, p1), pk2t(p2, p3));
        }
        const int m1 = m0 + 64;
        if (m1 < NPIX) load_tiles(m1, bi ^ 1);   // prefetch next K/V frags

        lgkm_barrier();   // ps[bi] visible; prefetch stays in flight

        // PV: O += V . P^T  (16B B-frags from swizzled ps, conflict-free)
#pragma unroll
        for (int s = 0; s < 2; ++s) {
            U48 Bp[4];
#pragma unroll
            for (int nt = 0; nt < 4; ++nt)
                Bp[nt].u = ps4[bi][(nt * 16 + nlo) * 8 + ((s * 4 + q) ^ (nlo & 7))];
#pragma unroll
            for (int ct = 0; ct < 4; ++ct)
#pragma unroll
                for (int nt = 0; nt < 4; ++nt)
                    acc[ct][nt] = __builtin_amdgcn_mfma_f32_16x16x32_bf16(
                        AvB[bi][s][ct].s, Bp[nt].s, acc[ct][nt], 0, 0, 0);
        }
    };

    load_tiles(0, 0);
    for (int m0 = 0; m0 < NPIX; m0 += 128) {   // 2 halves: static buffer idx
        body(m0, 0);
        body(m0 + 64, 1);
    }

    // ---- l reduction: over q-lanes (shfl) then over waves (LDS)
#pragma unroll
    for (int nt = 0; nt < 4; ++nt) {
        float v = lacc[nt];
        v += __shfl_xor(v, 16);
        v += __shfl_xor(v, 32);
        if (q == 0) ls[w][nt * 16 + nlo] = v;
    }
    __syncthreads();
    float linv[4];
#pragma unroll
    for (int nt = 0; nt < 4; ++nt) {
        const int n = nt * 16 + nlo;
        linv[nt] = 1.0f / (ls[0][n] + ls[1][n] + ls[2][n] + ls[3][n]);
    }

    // ---- epilogue: out = gamma * (O / l) + x
    const float gamma = gp[0];
    const float* xb2 = xg + (size_t)b * CN;
    float* ob = outg + (size_t)b * CN;
#pragma unroll
    for (int ct = 0; ct < 4; ++ct)
#pragma unroll
        for (int nt = 0; nt < 4; ++nt)
#pragma unroll
            for (int r = 0; r < 4; ++r) {
                const int c = w * 64 + ct * 16 + q * 4 + r;
                const int n = n0 + nt * 16 + nlo;
                const size_t off = (size_t)c * NPIX + n;
                ob[off] = fmaf(gamma, acc[ct][nt][r] * linv[nt], xb2[off]);
            }
}

// ---------------------------------------------------------------------------
extern "C" void kernel_launch(void* const* d_in, const int* in_sizes, int n_in,
                              void* d_out, int out_size, void* d_ws, size_t ws_size,
                              hipStream_t stream) {
    const float* x     = (const float*)d_in[0];   // (8,256,64,64)
    const float* Wq    = (const float*)d_in[1];   // (32,256)
    const float* Wk    = (const float*)d_in[2];   // (32,256)
    const float* Wv    = (const float*)d_in[3];   // (256,256)
    const float* gamma = (const float*)d_in[4];   // (1,)

    // ws: Q (B,N,32) bf16 2MB | K (B,N,32) bf16 2MB | V' (frag-granule) 16MB
    unsigned short* qws = (unsigned short*)d_ws;
    unsigned short* kws = qws + (size_t)8 * NPIX * 32;
    unsigned short* vws = kws + (size_t)8 * NPIX * 32;

    // batch = blockIdx.x (fast index): all blocks of a batch on one XCD.
    proj_fused<<<dim3(8, 64), 256, 0, stream>>>(x, Wq, Wk, Wv, qws, kws, vws);
    flash_v7<<<dim3(8, 64), 256, 0, stream>>>(qws, kws, vws, x, gamma,
                                              (float*)d_out);
}

// Round 6
// 183.451 us; speedup vs baseline: 2.0534x; 1.0200x over previous
//
#include <hip/hip_runtime.h>

// (B, C, H, W) = (8, 256, 64, 64); N = 4096; QK dim = 32.
#define NPIX 4096
#define CCH  256
#define CN   (CCH * NPIX)

typedef __attribute__((ext_vector_type(8))) short  short8;  // 8 bf16 (4 VGPRs)
typedef __attribute__((ext_vector_type(4))) float  f32x4;   // MFMA C/D frag

union U48 { uint4 u; short8 s; };

// pack two fp32 -> bf16 pair, truncation: single v_perm_b32
__device__ __forceinline__ unsigned pk2t(float lo, float hi) {
    return __builtin_amdgcn_perm(__float_as_uint(hi), __float_as_uint(lo),
                                 0x07060302u);
}
__device__ __forceinline__ unsigned short bf16t(float f) {
    return (unsigned short)(__float_as_uint(f) >> 16);
}

// Raw workgroup barrier: drains LDS ops only (global loads stay in flight).
__device__ __forceinline__ void lgkm_barrier() {
    asm volatile("s_waitcnt lgkmcnt(0)" ::: "memory");
    __builtin_amdgcn_s_barrier();
    asm volatile("" ::: "memory");
}

// 1/sqrt(32) * log2(e): scores come out in log2 domain -> v_exp_f32 direct
#define QSCALE 0.25503494f

// ---------------------------------------------------------------------------
// V' layout (bf16, 16B granules): granule g = ((((b*16+cb)*128+mb)*4+q)*16+cl)
// holds keys m = mb*32+q*8 .. +8 of channel ch = cb*16+cl.  Flash V A-frag
// load = base + lane*16: 1KB contiguous per wave instruction (r5: -43% flash).
//
// Confirmed cost model (r2-r5): dur ~ distinct-cache-lines-per-instruction
// x ~4-5 cyc, a per-CU serial resource, occupancy-invariant.
// ---------------------------------------------------------------------------

// ---------------------------------------------------------------------------
// Fused projections: out^T[n][d] = sum_c x[c][n] * W[d][c] for the stacked
// D = [Wq(32) | Wk(32) | Wv(256)] in 5 chunks of 64 rows.  x A-frags are
// loaded + bf16-packed ONCE per thread and reused across all 5 chunk GEMMs.
// r6 change: W staging COALESCED.  Old role split (dd=tid>>2, s4=tid&3)
// touched 64 quarter-used lines per instruction (16 rows x 4 col-positions)
// -> ~250 cyc/instr, 640 instrs/CU ~ 67 us = proj's whole overhead.  Now all
// 64 lanes load ONE row per instruction (lane l -> float4 at col 4l): 1KB
// contiguous, 8 fully-used lines.  Same swizzled ws4 layout on the write
// side (p = (L>>3)*8 + ((L&7)^(row&7)), L=lane>>1); read side unchanged.
// ---------------------------------------------------------------------------
__global__ __launch_bounds__(256, 2) void proj_fused(
    const float* __restrict__ xg, const float* __restrict__ Wq,
    const float* __restrict__ Wk, const float* __restrict__ Wv,
    unsigned short* __restrict__ qo, unsigned short* __restrict__ ko,
    unsigned short* __restrict__ vo)
{
    __shared__ uint4 ws4[64 * 32];   // W chunk: 64 d-rows x 32 bf16-granules
    const int tid = threadIdx.x;
    const int n0 = blockIdx.y * 64;
    const int b  = blockIdx.x;
    const int lane = tid & 63, w = tid >> 6;
    const int q = lane >> 4, nlo = lane & 15;
    const float* xb = xg + (size_t)b * CN;

    // ---- A-frags: x^T row n = n0+w*16+nlo, k-chunk c = ks*32+q*8..+8
    U48 A[8];
#pragma unroll
    for (int ks = 0; ks < 8; ++ks) {
        const float* xc = xb + (size_t)(ks * 32 + q * 8) * NPIX
                             + (n0 + w * 16 + nlo);
        float v0 = xc[0],        v1 = xc[NPIX],     v2 = xc[2 * NPIX],
              v3 = xc[3 * NPIX], v4 = xc[4 * NPIX], v5 = xc[5 * NPIX],
              v6 = xc[6 * NPIX], v7 = xc[7 * NPIX];
        A[ks].u = make_uint4(pk2t(v0, v1), pk2t(v2, v3),
                             pk2t(v4, v5), pk2t(v6, v7));
    }

    for (int cc = 0; cc < 5; ++cc) {
        lgkm_barrier();   // prior chunk's ds_reads done (consumed by MFMAs)
        {   // stage W chunk: wave w rows w*16..+16, one full row per instr
#pragma unroll
            for (int rr = 0; rr < 16; ++rr) {
                const int row = w * 16 + rr;
                const float* wr;
                if (cc == 0) wr = (row < 32) ? (Wq + row * CCH)
                                             : (Wk + (row - 32) * CCH);
                else         wr = Wv + (size_t)((cc - 1) * 64 + row) * CCH;
                float4 f = *(const float4*)(wr + lane * 4);   // 1KB contiguous
                const int L = lane >> 1;                      // logical granule
                const int p = (L >> 3) * 8 + ((L & 7) ^ (row & 7));
                *(uint2*)((char*)&ws4[row * 32 + p] + (lane & 1) * 8) =
                    make_uint2(pk2t(f.x, f.y), pk2t(f.z, f.w));
            }
        }
        lgkm_barrier();   // ws4 writes visible

        f32x4 acc[4];
#pragma unroll
        for (int dt = 0; dt < 4; ++dt) acc[dt] = (f32x4){0.f, 0.f, 0.f, 0.f};
#pragma unroll
        for (int ks = 0; ks < 8; ++ks)
#pragma unroll
            for (int dt = 0; dt < 4; ++dt) {
                U48 Bf;
                Bf.u = ws4[(dt * 16 + nlo) * 32 + (ks >> 1) * 8
                           + (((ks & 1) * 4 + q) ^ (nlo & 7))];
                acc[dt] = __builtin_amdgcn_mfma_f32_16x16x32_bf16(
                    A[ks].s, Bf.s, acc[dt], 0, 0, 0);
            }

        // ---- epilogue (C rows = n-offset q*4+r, cols = d = dt*16+nlo)
        if (cc == 0) {
#pragma unroll
            for (int dt = 0; dt < 4; ++dt) {
                const int d = dt * 16 + nlo;
#pragma unroll
                for (int r = 0; r < 4; ++r) {
                    const int n = n0 + w * 16 + q * 4 + r;
                    if (d < 32)
                        qo[((size_t)b * NPIX + n) * 32 + d] =
                            bf16t(acc[dt][r] * QSCALE);
                    else
                        ko[((size_t)b * NPIX + n) * 32 + (d - 32)] =
                            bf16t(acc[dt][r]);
                }
            }
        } else {
            // V' store: keys m = n0+w*16+q*4..+3 (uint2 = granule half q&1),
            // channel ch = (cc-1)*64 + dt*16 + nlo -> cb = (cc-1)*4+dt, cl=nlo
#pragma unroll
            for (int dt = 0; dt < 4; ++dt) {
                const int cb = (cc - 1) * 4 + dt;
                const int mb = (n0 >> 5) + (w >> 1);
                const int qc = (w & 1) * 2 + (q >> 1);
                const size_t gran =
                    ((((size_t)b * 16 + cb) * 128 + mb) * 4 + qc) * 16 + nlo;
                *(uint2*)((char*)vo + gran * 16 + (q & 1) * 8) =
                    make_uint2(pk2t(acc[dt][0], acc[dt][1]),
                               pk2t(acc[dt][2], acc[dt][3]));
            }
        }
    }
}

// ---------------------------------------------------------------------------
// Flash attention v7 (verified r5): 4 waves, P-LDS double-buffered, one
// lgkm-only barrier per body, K/V register double-buffered, V reads from the
// V' fragment-contiguous layout (base + lane*16, 1KB per wave instruction).
// ---------------------------------------------------------------------------
__global__ __launch_bounds__(256, 2) void flash_v7(
    const unsigned short* __restrict__ qg, const unsigned short* __restrict__ kg,
    const unsigned short* __restrict__ vg, const float* __restrict__ xg,
    const float* __restrict__ gp, float* __restrict__ outg)
{
    __shared__ uint4 ps4[2][64 * 8];   // P^T: [buf][n][swizzled m-granule]
    __shared__ float ls[4][64];        // per-wave l partials

    const int tid = threadIdx.x, lane = tid & 63, w = tid >> 6;
    const int q = lane >> 4, nlo = lane & 15;
    const int n0 = blockIdx.y * 64, b = blockIdx.x;

    const unsigned short* qb = qg + (size_t)b * NPIX * 32;
    const unsigned short* kb = kg + (size_t)b * NPIX * 32;

    U48 Bq[4];   // Q^T B-frags, loop-invariant
#pragma unroll
    for (int nt = 0; nt < 4; ++nt)
        Bq[nt].u = *(const uint4*)(qb + (size_t)(n0 + nt * 16 + nlo) * 32 + q * 8);

    f32x4 acc[4][4];   // [ct][nt]; wave w owns channels w*64..+64
#pragma unroll
    for (int ct = 0; ct < 4; ++ct)
#pragma unroll
        for (int nt = 0; nt < 4; ++nt) acc[ct][nt] = (f32x4){0.f, 0.f, 0.f, 0.f};
    float lacc[4] = {0.f, 0.f, 0.f, 0.f};

    U48 AkB[2], AvB[2][2][4];   // double-buffered K/V frags
    auto load_tiles = [&](int m0, int bi) {
        AkB[bi].u = *(const uint4*)(kb + (size_t)(m0 + w * 16 + nlo) * 32 + q * 8);
        const int mb = m0 >> 5;
#pragma unroll
        for (int s = 0; s < 2; ++s)
#pragma unroll
            for (int ct = 0; ct < 4; ++ct) {
                // V' granule: cb = w*4+ct, mb+s, q, cl=nlo -> lane*16 contiguous
                const size_t gran =
                    ((((size_t)b * 16 + w * 4 + ct) * 128 + (mb + s)) * 4 + q)
                        * 16 + nlo;
                AvB[bi][s][ct].u = *(const uint4*)((const char*)vg + gran * 16);
            }
    };
    auto body = [&](int m0, int bi) {
        // S^T: 4 MFMAs, rows m = m0+w*16+q*4+r, cols n = nt*16+nlo
        f32x4 St[4];
        const f32x4 z = {0.f, 0.f, 0.f, 0.f};
#pragma unroll
        for (int nt = 0; nt < 4; ++nt)
            St[nt] = __builtin_amdgcn_mfma_f32_16x16x32_bf16(
                AkB[bi].s, Bq[nt].s, z, 0, 0, 0);

#pragma unroll
        for (int nt = 0; nt < 4; ++nt) {
            float p0 = __builtin_amdgcn_exp2f(St[nt][0]);
            float p1 = __builtin_amdgcn_exp2f(St[nt][1]);
            float p2 = __builtin_amdgcn_exp2f(St[nt][2]);
            float p3 = __builtin_amdgcn_exp2f(St[nt][3]);
            lacc[nt] += (p0 + p1) + (p2 + p3);
            const int n = nt * 16 + nlo;
            ((uint2*)ps4[bi])[n * 16 + ((w * 2 + (q >> 1)) ^ (n & 7)) * 2 + (q & 1)] =
                make_uint2(pk2t(p0, p1), pk2t(p2, p3));
        }
        const int m1 = m0 + 64;
        if (m1 < NPIX) load_tiles(m1, bi ^ 1);   // prefetch next K/V frags

        lgkm_barrier();   // ps[bi] visible; prefetch stays in flight

        // PV: O += V . P^T  (16B B-frags from swizzled ps, conflict-free)
#pragma unroll
        for (int s = 0; s < 2; ++s) {
            U48 Bp[4];
#pragma unroll
            for (int nt = 0; nt < 4; ++nt)
                Bp[nt].u = ps4[bi][(nt * 16 + nlo) * 8 + ((s * 4 + q) ^ (nlo & 7))];
#pragma unroll
            for (int ct = 0; ct < 4; ++ct)
#pragma unroll
                for (int nt = 0; nt < 4; ++nt)
                    acc[ct][nt] = __builtin_amdgcn_mfma_f32_16x16x32_bf16(
                        AvB[bi][s][ct].s, Bp[nt].s, acc[ct][nt], 0, 0, 0);
        }
    };

    load_tiles(0, 0);
    for (int m0 = 0; m0 < NPIX; m0 += 128) {   // 2 halves: static buffer idx
        body(m0, 0);
        body(m0 + 64, 1);
    }

    // ---- l reduction: over q-lanes (shfl) then over waves (LDS)
#pragma unroll
    for (int nt = 0; nt < 4; ++nt) {
        float v = lacc[nt];
        v += __shfl_xor(v, 16);
        v += __shfl_xor(v, 32);
        if (q == 0) ls[w][nt * 16 + nlo] = v;
    }
    __syncthreads();
    float linv[4];
#pragma unroll
    for (int nt = 0; nt < 4; ++nt) {
        const int n = nt * 16 + nlo;
        linv[nt] = 1.0f / (ls[0][n] + ls[1][n] + ls[2][n] + ls[3][n]);
    }

    // ---- epilogue: out = gamma * (O / l) + x
    const float gamma = gp[0];
    const float* xb2 = xg + (size_t)b * CN;
    float* ob = outg + (size_t)b * CN;
#pragma unroll
    for (int ct = 0; ct < 4; ++ct)
#pragma unroll
        for (int nt = 0; nt < 4; ++nt)
#pragma unroll
            for (int r = 0; r < 4; ++r) {
                const int c = w * 64 + ct * 16 + q * 4 + r;
                const int n = n0 + nt * 16 + nlo;
                const size_t off = (size_t)c * NPIX + n;
                ob[off] = fmaf(gamma, acc[ct][nt][r] * linv[nt], xb2[off]);
            }
}

// ---------------------------------------------------------------------------
extern "C" void kernel_launch(void* const* d_in, const int* in_sizes, int n_in,
                              void* d_out, int out_size, void* d_ws, size_t ws_size,
                              hipStream_t stream) {
    const float* x     = (const float*)d_in[0];   // (8,256,64,64)
    const float* Wq    = (const float*)d_in[1];   // (32,256)
    const float* Wk    = (const float*)d_in[2];   // (32,256)
    const float* Wv    = (const float*)d_in[3];   // (256,256)
    const float* gamma = (const float*)d_in[4];   // (1,)

    // ws: Q (B,N,32) bf16 2MB | K (B,N,32) bf16 2MB | V' (frag-granule) 16MB
    unsigned short* qws = (unsigned short*)d_ws;
    unsigned short* kws = qws + (size_t)8 * NPIX * 32;
    unsigned short* vws = kws + (size_t)8 * NPIX * 32;

    // batch = blockIdx.x (fast index): all blocks of a batch on one XCD.
    proj_fused<<<dim3(8, 64), 256, 0, stream>>>(x, Wq, Wk, Wv, qws, kws, vws);
    flash_v7<<<dim3(8, 64), 256, 0, stream>>>(qws, kws, vws, x, gamma,
                                              (float*)d_out);
}

// Round 7
// 182.606 us; speedup vs baseline: 2.0629x; 1.0046x over previous
//
#include <hip/hip_runtime.h>

// (B, C, H, W) = (8, 256, 64, 64); N = 4096; QK dim = 32.
#define NPIX 4096
#define CCH  256
#define CN   (CCH * NPIX)

typedef __attribute__((ext_vector_type(8))) short  short8;  // 8 bf16 (4 VGPRs)
typedef __attribute__((ext_vector_type(4))) float  f32x4;   // MFMA C/D frag

union U48 { uint4 u; short8 s; };

// pack two fp32 -> bf16 pair, truncation: single v_perm_b32
__device__ __forceinline__ unsigned pk2t(float lo, float hi) {
    return __builtin_amdgcn_perm(__float_as_uint(hi), __float_as_uint(lo),
                                 0x07060302u);
}
__device__ __forceinline__ unsigned short bf16t(float f) {
    return (unsigned short)(__float_as_uint(f) >> 16);
}

// Raw workgroup barrier: drains LDS ops only (global loads stay in flight).
__device__ __forceinline__ void lgkm_barrier() {
    asm volatile("s_waitcnt lgkmcnt(0)" ::: "memory");
    __builtin_amdgcn_s_barrier();
    asm volatile("" ::: "memory");
}

// 1/sqrt(32) * log2(e): scores come out in log2 domain -> v_exp_f32 direct
#define QSCALE 0.25503494f

// ---------------------------------------------------------------------------
// V' layout (bf16, 16B granules): granule g = ((((b*16+cb)*128+mb)*4+q)*16+cl)
// holds keys m = mb*32+q*8 .. +8 of channel ch = cb*16+cl.  Flash V A-frag
// load = base + lane*16: 1KB contiguous per wave instruction (r5: -43% flash).
//
// Confirmed cost model (r2-r5): dur ~ distinct-cache-lines-per-instruction
// x ~4-5 cyc, a per-CU serial resource, occupancy-invariant.  With scatter
// fixed, flash is latency-bound (r6: MfmaUtil 41, VALU 30, HBM 10, occ 18)
// -> raise waves/SIMD 2->4 (this was useless in r2 ONLY because the scatter
// resource was occupancy-invariant; that resource is gone now).
// ---------------------------------------------------------------------------

// ---------------------------------------------------------------------------
// Fused projections (r6 version: coalesced W staging, V' stores).
// ---------------------------------------------------------------------------
__global__ __launch_bounds__(256, 2) void proj_fused(
    const float* __restrict__ xg, const float* __restrict__ Wq,
    const float* __restrict__ Wk, const float* __restrict__ Wv,
    unsigned short* __restrict__ qo, unsigned short* __restrict__ ko,
    unsigned short* __restrict__ vo)
{
    __shared__ uint4 ws4[64 * 32];   // W chunk: 64 d-rows x 32 bf16-granules
    const int tid = threadIdx.x;
    const int n0 = blockIdx.y * 64;
    const int b  = blockIdx.x;
    const int lane = tid & 63, w = tid >> 6;
    const int q = lane >> 4, nlo = lane & 15;
    const float* xb = xg + (size_t)b * CN;

    // ---- A-frags: x^T row n = n0+w*16+nlo, k-chunk c = ks*32+q*8..+8
    U48 A[8];
#pragma unroll
    for (int ks = 0; ks < 8; ++ks) {
        const float* xc = xb + (size_t)(ks * 32 + q * 8) * NPIX
                             + (n0 + w * 16 + nlo);
        float v0 = xc[0],        v1 = xc[NPIX],     v2 = xc[2 * NPIX],
              v3 = xc[3 * NPIX], v4 = xc[4 * NPIX], v5 = xc[5 * NPIX],
              v6 = xc[6 * NPIX], v7 = xc[7 * NPIX];
        A[ks].u = make_uint4(pk2t(v0, v1), pk2t(v2, v3),
                             pk2t(v4, v5), pk2t(v6, v7));
    }

    for (int cc = 0; cc < 5; ++cc) {
        lgkm_barrier();   // prior chunk's ds_reads done (consumed by MFMAs)
        {   // stage W chunk: wave w rows w*16..+16, one full row per instr
#pragma unroll
            for (int rr = 0; rr < 16; ++rr) {
                const int row = w * 16 + rr;
                const float* wr;
                if (cc == 0) wr = (row < 32) ? (Wq + row * CCH)
                                             : (Wk + (row - 32) * CCH);
                else         wr = Wv + (size_t)((cc - 1) * 64 + row) * CCH;
                float4 f = *(const float4*)(wr + lane * 4);   // 1KB contiguous
                const int L = lane >> 1;                      // logical granule
                const int p = (L >> 3) * 8 + ((L & 7) ^ (row & 7));
                *(uint2*)((char*)&ws4[row * 32 + p] + (lane & 1) * 8) =
                    make_uint2(pk2t(f.x, f.y), pk2t(f.z, f.w));
            }
        }
        lgkm_barrier();   // ws4 writes visible

        f32x4 acc[4];
#pragma unroll
        for (int dt = 0; dt < 4; ++dt) acc[dt] = (f32x4){0.f, 0.f, 0.f, 0.f};
#pragma unroll
        for (int ks = 0; ks < 8; ++ks)
#pragma unroll
            for (int dt = 0; dt < 4; ++dt) {
                U48 Bf;
                Bf.u = ws4[(dt * 16 + nlo) * 32 + (ks >> 1) * 8
                           + (((ks & 1) * 4 + q) ^ (nlo & 7))];
                acc[dt] = __builtin_amdgcn_mfma_f32_16x16x32_bf16(
                    A[ks].s, Bf.s, acc[dt], 0, 0, 0);
            }

        // ---- epilogue (C rows = n-offset q*4+r, cols = d = dt*16+nlo)
        if (cc == 0) {
#pragma unroll
            for (int dt = 0; dt < 4; ++dt) {
                const int d = dt * 16 + nlo;
#pragma unroll
                for (int r = 0; r < 4; ++r) {
                    const int n = n0 + w * 16 + q * 4 + r;
                    if (d < 32)
                        qo[((size_t)b * NPIX + n) * 32 + d] =
                            bf16t(acc[dt][r] * QSCALE);
                    else
                        ko[((size_t)b * NPIX + n) * 32 + (d - 32)] =
                            bf16t(acc[dt][r]);
                }
            }
        } else {
            // V' store: keys m = n0+w*16+q*4..+3 (uint2 = granule half q&1),
            // channel ch = (cc-1)*64 + dt*16 + nlo -> cb = (cc-1)*4+dt, cl=nlo
#pragma unroll
            for (int dt = 0; dt < 4; ++dt) {
                const int cb = (cc - 1) * 4 + dt;
                const int mb = (n0 >> 5) + (w >> 1);
                const int qc = (w & 1) * 2 + (q >> 1);
                const size_t gran =
                    ((((size_t)b * 16 + cb) * 128 + mb) * 4 + qc) * 16 + nlo;
                *(uint2*)((char*)vo + gran * 16 + (q & 1) * 8) =
                    make_uint2(pk2t(acc[dt][0], acc[dt][1]),
                               pk2t(acc[dt][2], acc[dt][3]));
            }
        }
    }
}

// ---------------------------------------------------------------------------
// Flash attention v8: 512 threads (8 waves) -> 4 waves/SIMD (was 2), for the
// now latency-bound regime.  Composition of verified pieces:
//  - v4's 8-wave geometry (QK: wave=(wm,h) m-strip x n-half; PV: 32 ch/wave;
//    its P-write swizzle, l-reduction, epilogue)  [passed r2]
//  - v5/v7's single lgkm-only barrier per body + P-LDS double-buffer
//    [passed r3/r5]
//  - V' fragment-contiguous V loads (1KB/instruction)  [passed r5/r6]
// Prefetch is issued immediately after the QK MFMAs (max in-flight window).
// ---------------------------------------------------------------------------
__global__ __launch_bounds__(512, 4) void flash_v8(
    const unsigned short* __restrict__ qg, const unsigned short* __restrict__ kg,
    const unsigned short* __restrict__ vg, const float* __restrict__ xg,
    const float* __restrict__ gp, float* __restrict__ outg)
{
    __shared__ uint4 ps4[2][64 * 8];   // P^T: [buf][n][swizzled m-granule]
    __shared__ float ls2[4][64];       // per-(m-strip) l partials

    const int tid = threadIdx.x, lane = tid & 63, w = tid >> 6;   // w in 0..7
    const int q = lane >> 4, nlo = lane & 15;
    const int wm = w & 3;              // QK m-strip within 64-key body
    const int h  = w >> 2;             // QK n-half
    const int n0 = blockIdx.y * 64, b = blockIdx.x;

    const unsigned short* qb = qg + (size_t)b * NPIX * 32;
    const unsigned short* kb = kg + (size_t)b * NPIX * 32;

    U48 Bq[2];   // Q^T B-frags for this wave's n-half, loop-invariant
#pragma unroll
    for (int ntl = 0; ntl < 2; ++ntl)
        Bq[ntl].u = *(const uint4*)(
            qb + (size_t)(n0 + h * 32 + ntl * 16 + nlo) * 32 + q * 8);

    f32x4 acc[2][4];   // [ct][nt]; wave w owns channels w*32..+32
#pragma unroll
    for (int ct = 0; ct < 2; ++ct)
#pragma unroll
        for (int nt = 0; nt < 4; ++nt) acc[ct][nt] = (f32x4){0.f, 0.f, 0.f, 0.f};
    float lacc[2] = {0.f, 0.f};

    U48 AkB[2], AvB[2][2][2];   // double-buffered K/V frags [buf][s][ct]
    auto load_tiles = [&](int m0, int bi) {
        AkB[bi].u = *(const uint4*)(kb + (size_t)(m0 + wm * 16 + nlo) * 32 + q * 8);
        const int mb = m0 >> 5;
#pragma unroll
        for (int s = 0; s < 2; ++s)
#pragma unroll
            for (int ct = 0; ct < 2; ++ct) {
                // V' granule: cb = w*2+ct (ch = w*32+ct*16+nlo), keys
                // (mb+s)*32 + q*8 -> address = base + lane*16 (contiguous)
                const size_t gran =
                    ((((size_t)b * 16 + w * 2 + ct) * 128 + (mb + s)) * 4 + q)
                        * 16 + nlo;
                AvB[bi][s][ct].u = *(const uint4*)((const char*)vg + gran * 16);
            }
    };
    auto body = [&](int m0, int bi) {
        // S^T: 2 MFMAs, rows m = m0+wm*16+q*4+r, cols n = h*32+ntl*16+nlo
        f32x4 St[2];
        const f32x4 z = {0.f, 0.f, 0.f, 0.f};
#pragma unroll
        for (int ntl = 0; ntl < 2; ++ntl)
            St[ntl] = __builtin_amdgcn_mfma_f32_16x16x32_bf16(
                AkB[bi].s, Bq[ntl].s, z, 0, 0, 0);

        const int m1 = m0 + 64;
        if (m1 < NPIX) load_tiles(m1, bi ^ 1);   // prefetch next K/V frags

#pragma unroll
        for (int ntl = 0; ntl < 2; ++ntl) {
            float p0 = __builtin_amdgcn_exp2f(St[ntl][0]);
            float p1 = __builtin_amdgcn_exp2f(St[ntl][1]);
            float p2 = __builtin_amdgcn_exp2f(St[ntl][2]);
            float p3 = __builtin_amdgcn_exp2f(St[ntl][3]);
            lacc[ntl] += (p0 + p1) + (p2 + p3);
            const int n = h * 32 + ntl * 16 + nlo;
            const int g = wm * 4 + q;   // 8B m-granule (m = wm*16+q*4)
            ((uint2*)ps4[bi])[n * 16 + (g ^ ((n & 7) << 1))] =
                make_uint2(pk2t(p0, p1), pk2t(p2, p3));
        }

        lgkm_barrier();   // ps[bi] visible; global prefetch stays in flight

        // PV: O += V . P^T  (16B B-frags from swizzled ps, conflict-free)
#pragma unroll
        for (int s = 0; s < 2; ++s) {
            U48 Bp[4];
#pragma unroll
            for (int nt = 0; nt < 4; ++nt)
                Bp[nt].u = ps4[bi][(nt * 16 + nlo) * 8 + ((s * 4 + q) ^ (nlo & 7))];
#pragma unroll
            for (int ct = 0; ct < 2; ++ct)
#pragma unroll
                for (int nt = 0; nt < 4; ++nt)
                    acc[ct][nt] = __builtin_amdgcn_mfma_f32_16x16x32_bf16(
                        AvB[bi][s][ct].s, Bp[nt].s, acc[ct][nt], 0, 0, 0);
        }
    };

    load_tiles(0, 0);
    for (int m0 = 0; m0 < NPIX; m0 += 128) {   // 2 halves: static buffer idx
        body(m0, 0);
        body(m0 + 64, 1);
    }

    // ---- l reduction: over q-lanes (shfl) then over the 4 m-strips (LDS)
#pragma unroll
    for (int ntl = 0; ntl < 2; ++ntl) {
        float v = lacc[ntl];
        v += __shfl_xor(v, 16);
        v += __shfl_xor(v, 32);
        if (q == 0) ls2[wm][h * 32 + ntl * 16 + nlo] = v;
    }
    __syncthreads();
    float linv[4];
#pragma unroll
    for (int nt = 0; nt < 4; ++nt) {
        const int n = nt * 16 + nlo;
        linv[nt] = 1.0f / (ls2[0][n] + ls2[1][n] + ls2[2][n] + ls2[3][n]);
    }

    // ---- epilogue: out = gamma * (O / l) + x
    const float gamma = gp[0];
    const float* xb2 = xg + (size_t)b * CN;
    float* ob = outg + (size_t)b * CN;
#pragma unroll
    for (int ct = 0; ct < 2; ++ct)
#pragma unroll
        for (int nt = 0; nt < 4; ++nt)
#pragma unroll
            for (int r = 0; r < 4; ++r) {
                const int c = w * 32 + ct * 16 + q * 4 + r;
                const int n = n0 + nt * 16 + nlo;
                const size_t off = (size_t)c * NPIX + n;
                ob[off] = fmaf(gamma, acc[ct][nt][r] * linv[nt], xb2[off]);
            }
}

// ---------------------------------------------------------------------------
extern "C" void kernel_launch(void* const* d_in, const int* in_sizes, int n_in,
                              void* d_out, int out_size, void* d_ws, size_t ws_size,
                              hipStream_t stream) {
    const float* x     = (const float*)d_in[0];   // (8,256,64,64)
    const float* Wq    = (const float*)d_in[1];   // (32,256)
    const float* Wk    = (const float*)d_in[2];   // (32,256)
    const float* Wv    = (const float*)d_in[3];   // (256,256)
    const float* gamma = (const float*)d_in[4];   // (1,)

    // ws: Q (B,N,32) bf16 2MB | K (B,N,32) bf16 2MB | V' (frag-granule) 16MB
    unsigned short* qws = (unsigned short*)d_ws;
    unsigned short* kws = qws + (size_t)8 * NPIX * 32;
    unsigned short* vws = kws + (size_t)8 * NPIX * 32;

    // batch = blockIdx.x (fast index): all blocks of a batch on one XCD.
    proj_fused<<<dim3(8, 64), 256, 0, stream>>>(x, Wq, Wk, Wv, qws, kws, vws);
    flash_v8<<<dim3(8, 64), 512, 0, stream>>>(qws, kws, vws, x, gamma,
                                              (float*)d_out);
}

// Round 8
// 179.939 us; speedup vs baseline: 2.0935x; 1.0148x over previous
//
#include <hip/hip_runtime.h>

// (B, C, H, W) = (8, 256, 64, 64); N = 4096; QK dim = 32.
#define NPIX 4096
#define CCH  256
#define CN   (CCH * NPIX)

typedef __attribute__((ext_vector_type(8))) short  short8;  // 8 bf16 (4 VGPRs)
typedef __attribute__((ext_vector_type(4))) float  f32x4;   // MFMA C/D frag

union U48 { uint4 u; short8 s; };

// pack two fp32 -> bf16 pair, truncation: single v_perm_b32
__device__ __forceinline__ unsigned pk2t(float lo, float hi) {
    return __builtin_amdgcn_perm(__float_as_uint(hi), __float_as_uint(lo),
                                 0x07060302u);
}
__device__ __forceinline__ unsigned short bf16t(float f) {
    return (unsigned short)(__float_as_uint(f) >> 16);
}

// Raw workgroup barrier: drains LDS ops only (global loads stay in flight).
__device__ __forceinline__ void lgkm_barrier() {
    asm volatile("s_waitcnt lgkmcnt(0)" ::: "memory");
    __builtin_amdgcn_s_barrier();
    asm volatile("" ::: "memory");
}

// 1/sqrt(32) * log2(e): scores come out in log2 domain -> v_exp_f32 direct
#define QSCALE 0.25503494f

// ---------------------------------------------------------------------------
// Cost model (fitted r2-r7, all six variants): dur ~ distinct-128B-lines
// touched per CU x ~4.3 cyc -- a per-CU serial resource, occupancy-invariant.
// v7/v8 (41K lines/CU, identical) both = 81 us.  The only remaining lever:
// fewer K/V sweeps per CU -> 128-query blocks, grid (8,32) = 1 block/CU.
//
// V' layout (bf16, 16B granules): granule g = ((((b*16+cb)*128+mb)*4+q)*16+cl)
// holds keys m = mb*32+q*8 .. +8 of channel ch = cb*16+cl.  Flash V A-frag
// load = base + lane*16: 1KB contiguous per wave instruction.
// ---------------------------------------------------------------------------

// ---------------------------------------------------------------------------
// Fused projections (r6 version: coalesced W staging, V' stores).
// ---------------------------------------------------------------------------
__global__ __launch_bounds__(256, 2) void proj_fused(
    const float* __restrict__ xg, const float* __restrict__ Wq,
    const float* __restrict__ Wk, const float* __restrict__ Wv,
    unsigned short* __restrict__ qo, unsigned short* __restrict__ ko,
    unsigned short* __restrict__ vo)
{
    __shared__ uint4 ws4[64 * 32];   // W chunk: 64 d-rows x 32 bf16-granules
    const int tid = threadIdx.x;
    const int n0 = blockIdx.y * 64;
    const int b  = blockIdx.x;
    const int lane = tid & 63, w = tid >> 6;
    const int q = lane >> 4, nlo = lane & 15;
    const float* xb = xg + (size_t)b * CN;

    // ---- A-frags: x^T row n = n0+w*16+nlo, k-chunk c = ks*32+q*8..+8
    U48 A[8];
#pragma unroll
    for (int ks = 0; ks < 8; ++ks) {
        const float* xc = xb + (size_t)(ks * 32 + q * 8) * NPIX
                             + (n0 + w * 16 + nlo);
        float v0 = xc[0],        v1 = xc[NPIX],     v2 = xc[2 * NPIX],
              v3 = xc[3 * NPIX], v4 = xc[4 * NPIX], v5 = xc[5 * NPIX],
              v6 = xc[6 * NPIX], v7 = xc[7 * NPIX];
        A[ks].u = make_uint4(pk2t(v0, v1), pk2t(v2, v3),
                             pk2t(v4, v5), pk2t(v6, v7));
    }

    for (int cc = 0; cc < 5; ++cc) {
        lgkm_barrier();   // prior chunk's ds_reads done (consumed by MFMAs)
        {   // stage W chunk: wave w rows w*16..+16, one full row per instr
#pragma unroll
            for (int rr = 0; rr < 16; ++rr) {
                const int row = w * 16 + rr;
                const float* wr;
                if (cc == 0) wr = (row < 32) ? (Wq + row * CCH)
                                             : (Wk + (row - 32) * CCH);
                else         wr = Wv + (size_t)((cc - 1) * 64 + row) * CCH;
                float4 f = *(const float4*)(wr + lane * 4);   // 1KB contiguous
                const int L = lane >> 1;                      // logical granule
                const int p = (L >> 3) * 8 + ((L & 7) ^ (row & 7));
                *(uint2*)((char*)&ws4[row * 32 + p] + (lane & 1) * 8) =
                    make_uint2(pk2t(f.x, f.y), pk2t(f.z, f.w));
            }
        }
        lgkm_barrier();   // ws4 writes visible

        f32x4 acc[4];
#pragma unroll
        for (int dt = 0; dt < 4; ++dt) acc[dt] = (f32x4){0.f, 0.f, 0.f, 0.f};
#pragma unroll
        for (int ks = 0; ks < 8; ++ks)
#pragma unroll
            for (int dt = 0; dt < 4; ++dt) {
                U48 Bf;
                Bf.u = ws4[(dt * 16 + nlo) * 32 + (ks >> 1) * 8
                           + (((ks & 1) * 4 + q) ^ (nlo & 7))];
                acc[dt] = __builtin_amdgcn_mfma_f32_16x16x32_bf16(
                    A[ks].s, Bf.s, acc[dt], 0, 0, 0);
            }

        // ---- epilogue (C rows = n-offset q*4+r, cols = d = dt*16+nlo)
        if (cc == 0) {
#pragma unroll
            for (int dt = 0; dt < 4; ++dt) {
                const int d = dt * 16 + nlo;
#pragma unroll
                for (int r = 0; r < 4; ++r) {
                    const int n = n0 + w * 16 + q * 4 + r;
                    if (d < 32)
                        qo[((size_t)b * NPIX + n) * 32 + d] =
                            bf16t(acc[dt][r] * QSCALE);
                    else
                        ko[((size_t)b * NPIX + n) * 32 + (d - 32)] =
                            bf16t(acc[dt][r]);
                }
            }
        } else {
            // V' store: keys m = n0+w*16+q*4..+3 (uint2 = granule half q&1),
            // channel ch = (cc-1)*64 + dt*16 + nlo -> cb = (cc-1)*4+dt, cl=nlo
#pragma unroll
            for (int dt = 0; dt < 4; ++dt) {
                const int cb = (cc - 1) * 4 + dt;
                const int mb = (n0 >> 5) + (w >> 1);
                const int qc = (w & 1) * 2 + (q >> 1);
                const size_t gran =
                    ((((size_t)b * 16 + cb) * 128 + mb) * 4 + qc) * 16 + nlo;
                *(uint2*)((char*)vo + gran * 16 + (q & 1) * 8) =
                    make_uint2(pk2t(acc[dt][0], acc[dt][1]),
                               pk2t(acc[dt][2], acc[dt][3]));
            }
        }
    }
}

// ---------------------------------------------------------------------------
// Flash attention v9: 128-QUERY blocks, grid (8,32) = 256 blocks = 1/CU
// (one batch per XCD, no tail).  Halves the per-CU K/V line-touch budget
// vs v8 (the identified wall).  Body structure is verified v8: 8 waves,
// single lgkm-only barrier per body, P-LDS double-buffered (2 x 16 KB),
// V' fragment-contiguous loads, K/V register double-buffered.
// QK: wave (wm = w&3, h = w>>2): m-strip wm*16, n-half h*64 (4 MFMAs).
// PV: wave owns channels w*32..+32 for all 128 queries: acc[2][8].
// ---------------------------------------------------------------------------
__global__ __launch_bounds__(512, 2) void flash_v9(
    const unsigned short* __restrict__ qg, const unsigned short* __restrict__ kg,
    const unsigned short* __restrict__ vg, const float* __restrict__ xg,
    const float* __restrict__ gp, float* __restrict__ outg)
{
    __shared__ uint4 ps4[2][128 * 8];   // P^T: [buf][n][swizzled m-granule]
    __shared__ float ls2[4][128];       // per-(m-strip) l partials

    const int tid = threadIdx.x, lane = tid & 63, w = tid >> 6;   // w in 0..7
    const int q = lane >> 4, nlo = lane & 15;
    const int wm = w & 3;              // QK m-strip within 64-key body
    const int h  = w >> 2;             // QK n-half (64 queries each)
    const int n0 = blockIdx.y * 128, b = blockIdx.x;

    const unsigned short* qb = qg + (size_t)b * NPIX * 32;
    const unsigned short* kb = kg + (size_t)b * NPIX * 32;

    U48 Bq[4];   // Q^T B-frags for this wave's n-half, loop-invariant
#pragma unroll
    for (int ntl = 0; ntl < 4; ++ntl)
        Bq[ntl].u = *(const uint4*)(
            qb + (size_t)(n0 + h * 64 + ntl * 16 + nlo) * 32 + q * 8);

    f32x4 acc[2][8];   // [ct][nt]; wave w owns channels w*32..+32
#pragma unroll
    for (int ct = 0; ct < 2; ++ct)
#pragma unroll
        for (int nt = 0; nt < 8; ++nt) acc[ct][nt] = (f32x4){0.f, 0.f, 0.f, 0.f};
    float lacc[4] = {0.f, 0.f, 0.f, 0.f};

    U48 AkB[2], AvB[2][2][2];   // double-buffered K/V frags [buf][s][ct]
    auto load_tiles = [&](int m0, int bi) {
        AkB[bi].u = *(const uint4*)(kb + (size_t)(m0 + wm * 16 + nlo) * 32 + q * 8);
        const int mb = m0 >> 5;
#pragma unroll
        for (int s = 0; s < 2; ++s)
#pragma unroll
            for (int ct = 0; ct < 2; ++ct) {
                // V' granule: cb = w*2+ct (ch = w*32+ct*16+nlo), keys
                // (mb+s)*32 + q*8 -> address = base + lane*16 (contiguous)
                const size_t gran =
                    ((((size_t)b * 16 + w * 2 + ct) * 128 + (mb + s)) * 4 + q)
                        * 16 + nlo;
                AvB[bi][s][ct].u = *(const uint4*)((const char*)vg + gran * 16);
            }
    };
    auto body = [&](int m0, int bi) {
        // S^T: 4 MFMAs, rows m = m0+wm*16+q*4+r, cols n = h*64+ntl*16+nlo
        f32x4 St[4];
        const f32x4 z = {0.f, 0.f, 0.f, 0.f};
#pragma unroll
        for (int ntl = 0; ntl < 4; ++ntl)
            St[ntl] = __builtin_amdgcn_mfma_f32_16x16x32_bf16(
                AkB[bi].s, Bq[ntl].s, z, 0, 0, 0);

        const int m1 = m0 + 64;
        if (m1 < NPIX) load_tiles(m1, bi ^ 1);   // prefetch next K/V frags

#pragma unroll
        for (int ntl = 0; ntl < 4; ++ntl) {
            float p0 = __builtin_amdgcn_exp2f(St[ntl][0]);
            float p1 = __builtin_amdgcn_exp2f(St[ntl][1]);
            float p2 = __builtin_amdgcn_exp2f(St[ntl][2]);
            float p3 = __builtin_amdgcn_exp2f(St[ntl][3]);
            lacc[ntl] += (p0 + p1) + (p2 + p3);
            const int n = h * 64 + ntl * 16 + nlo;
            const int g = wm * 4 + q;   // 8B m-granule (m = wm*16+q*4)
            ((uint2*)ps4[bi])[n * 16 + (g ^ ((n & 7) << 1))] =
                make_uint2(pk2t(p0, p1), pk2t(p2, p3));
        }

        lgkm_barrier();   // ps[bi] visible; global prefetch stays in flight

        // PV: O += V . P^T  (16B B-frags from swizzled ps, conflict-free)
#pragma unroll
        for (int s = 0; s < 2; ++s) {
            U48 Bp[8];
#pragma unroll
            for (int nt = 0; nt < 8; ++nt)
                Bp[nt].u = ps4[bi][(nt * 16 + nlo) * 8 + ((s * 4 + q) ^ (nlo & 7))];
#pragma unroll
            for (int ct = 0; ct < 2; ++ct)
#pragma unroll
                for (int nt = 0; nt < 8; ++nt)
                    acc[ct][nt] = __builtin_amdgcn_mfma_f32_16x16x32_bf16(
                        AvB[bi][s][ct].s, Bp[nt].s, acc[ct][nt], 0, 0, 0);
        }
    };

    load_tiles(0, 0);
    for (int m0 = 0; m0 < NPIX; m0 += 128) {   // 2 halves: static buffer idx
        body(m0, 0);
        body(m0 + 64, 1);
    }

    // ---- l reduction: over q-lanes (shfl) then over the 4 m-strips (LDS)
#pragma unroll
    for (int ntl = 0; ntl < 4; ++ntl) {
        float v = lacc[ntl];
        v += __shfl_xor(v, 16);
        v += __shfl_xor(v, 32);
        if (q == 0) ls2[wm][h * 64 + ntl * 16 + nlo] = v;
    }
    __syncthreads();
    float linv[8];
#pragma unroll
    for (int nt = 0; nt < 8; ++nt) {
        const int n = nt * 16 + nlo;
        linv[nt] = 1.0f / (ls2[0][n] + ls2[1][n] + ls2[2][n] + ls2[3][n]);
    }

    // ---- epilogue: out = gamma * (O / l) + x
    const float gamma = gp[0];
    const float* xb2 = xg + (size_t)b * CN;
    float* ob = outg + (size_t)b * CN;
#pragma unroll
    for (int ct = 0; ct < 2; ++ct)
#pragma unroll
        for (int nt = 0; nt < 8; ++nt)
#pragma unroll
            for (int r = 0; r < 4; ++r) {
                const int c = w * 32 + ct * 16 + q * 4 + r;
                const int n = n0 + nt * 16 + nlo;
                const size_t off = (size_t)c * NPIX + n;
                ob[off] = fmaf(gamma, acc[ct][nt][r] * linv[nt], xb2[off]);
            }
}

// ---------------------------------------------------------------------------
extern "C" void kernel_launch(void* const* d_in, const int* in_sizes, int n_in,
                              void* d_out, int out_size, void* d_ws, size_t ws_size,
                              hipStream_t stream) {
    const float* x     = (const float*)d_in[0];   // (8,256,64,64)
    const float* Wq    = (const float*)d_in[1];   // (32,256)
    const float* Wk    = (const float*)d_in[2];   // (32,256)
    const float* Wv    = (const float*)d_in[3];   // (256,256)
    const float* gamma = (const float*)d_in[4];   // (1,)

    // ws: Q (B,N,32) bf16 2MB | K (B,N,32) bf16 2MB | V' (frag-granule) 16MB
    unsigned short* qws = (unsigned short*)d_ws;
    unsigned short* kws = qws + (size_t)8 * NPIX * 32;
    unsigned short* vws = kws + (size_t)8 * NPIX * 32;

    // batch = blockIdx.x (fast index): all blocks of a batch on one XCD.
    proj_fused<<<dim3(8, 64), 256, 0, stream>>>(x, Wq, Wk, Wv, qws, kws, vws);
    flash_v9<<<dim3(8, 32), 512, 0, stream>>>(qws, kws, vws, x, gamma,
                                              (float*)d_out);
}